// Round 14
// baseline (104.669 us; speedup 1.0000x reference)
//
#include <hip/hip_runtime.h>
#include <hip/hip_cooperative_groups.h>
#include <math.h>

#define B     8
#define C     1024
#define M     8
#define HW    4096
#define EPS   1e-6f
#define GAIN  0.3f

#define TPB   1024       // 16 waves -> 16 waves/CU at 1 block/CU
#define TILE  128        // hw per block
#define NTILE 32         // HW/TILE; grid = B*NTILE = 256
#define NG    32         // channel groups (g = tid>>5)
#define CPG   32         // channels per group
#define SLOTS 32         // float4 hw slots (s = tid&31)

typedef float floatx4 __attribute__((ext_vector_type(4)));

// ws: [256][2] stat partials = 2 KB
__global__ __launch_bounds__(TPB, 4) void fused(const float* __restrict__ z,
                                                const float* __restrict__ Wd,
                                                float* __restrict__ out,
                                                float* __restrict__ ws) {
    // LDS: 32 + 64 + 16 + 8 KB = ~120 KB -> 1 block/CU
    __shared__ float Wl[C][M];                         // rotated W
    __shared__ __align__(16) float4 scr[NG][4][SLOTS]; // cross-group yz (half-M rounds)
    __shared__ __align__(16) float4 yzacc[M][SLOTS];   // block's reduced yz
    __shared__ float sred[2 * TPB];                    // stats tree
    __shared__ float sh_s[M];
    __shared__ float sh_ms[2];

    const int tid = threadIdx.x;
    const int bid = blockIdx.x;
    const int b   = bid >> 5;
    const int t   = bid & 31;
    const int g   = tid >> 5;          // 2 groups per wave (rotation makes banks differ)
    const int s   = tid & 31;
    const int rot = g & 7;             // == (c>>5)&7 for all c in this group

    // W -> rotated LDS: Wl[c][(m+(c>>5))&7] = W[m][c]
#pragma unroll
    for (int k = 0; k < 8; ++k) {
        int idx = k * TPB + tid;       // flat m*C + c
        int m = idx >> 10, c = idx & 1023;
        Wl[c][(m + (c >> 5)) & 7] = Wd[idx];
    }
    __syncthreads();

    const size_t zoff = ((size_t)(b * C + g * CPG)) * HW + t * TILE + s * 4;

    // ---------------- phase A: read z once -> stats + ym -------------------
    float4 ym[M];
#pragma unroll
    for (int m = 0; m < M; ++m) ym[m] = make_float4(0.f, 0.f, 0.f, 0.f);
    float su = 0.f, sq = 0.f;

#pragma unroll 8
    for (int ci = 0; ci < CPG; ++ci) {
        float4 v = *reinterpret_cast<const float4*>(z + zoff + (size_t)ci * HW);
        su += (v.x + v.y) + (v.z + v.w);
        sq += v.x * v.x + v.y * v.y + v.z * v.z + v.w * v.w;
        const float* wc = &Wl[g * CPG + ci][0];
#pragma unroll
        for (int m = 0; m < M; ++m) {          // static acc index
            float w = wc[(m + rot) & 7];
            ym[m].x += w * v.x; ym[m].y += w * v.y;
            ym[m].z += w * v.z; ym[m].w += w * v.w;
        }
    }

    // stats tree -> ws[bid]
    sred[tid]       = su;
    sred[TPB + tid] = sq;
    // cross-group yz reduce: 2 rounds of 4 m's through 64 KB scr
#pragma unroll
    for (int r = 0; r < 2; ++r) {
        __syncthreads();
#pragma unroll
        for (int mm = 0; mm < 4; ++mm) scr[g][mm][s] = ym[r * 4 + mm];
        __syncthreads();
        if (tid < 128) {
            const int mm = tid >> 5, s2 = tid & 31;
            float4 a = make_float4(0.f, 0.f, 0.f, 0.f);
#pragma unroll
            for (int g2 = 0; g2 < NG; ++g2) {
                float4 p = scr[g2][mm][s2];
                a.x += p.x; a.y += p.y; a.z += p.z; a.w += p.w;
            }
            yzacc[r * 4 + mm][s2] = a;
        }
    }
    __syncthreads();
    for (int r = TPB / 2; r > 0; r >>= 1) {
        if (tid < r) {
            sred[tid]       += sred[tid + r];
            sred[TPB + tid] += sred[TPB + tid + r];
        }
        __syncthreads();
    }
    if (tid == 0) {
        ws[bid * 2]     = sred[0];
        ws[bid * 2 + 1] = sred[TPB];
    }

    cooperative_groups::this_grid().sync();

    // ---------------- finalize scalars in-block ----------------------------
    if (tid < 64) {            // mu/istd from batch b's 32 block partials
        float pu = 0.f, pq = 0.f;
        if (tid < 32) {
            pu = ws[(b * 32 + tid) * 2];
            pq = ws[(b * 32 + tid) * 2 + 1];
        }
#pragma unroll
        for (int o = 16; o > 0; o >>= 1) {
            pu += __shfl_down(pu, o);
            pq += __shfl_down(pq, o);
        }
        if (tid == 0) {
            const float invN = 1.0f / (float)(C * HW);
            float mu  = pu * invN;
            float var = pq * invN - mu * mu;
            sh_ms[0] = mu;
            sh_ms[1] = 1.0f / sqrtf(var + EPS);
        }
    } else if (tid < 128) {    // s[m] from LDS W copy
        const int m = (tid - 64) >> 3, k = (tid - 64) & 7;
        float p = 0.f;
        for (int j = 0; j < 128; ++j) {
            int c = k * 128 + j;
            p += Wl[c][(m + (c >> 5)) & 7];
        }
        p += __shfl_down(p, 4);
        p += __shfl_down(p, 2);
        p += __shfl_down(p, 1);
        if (k == 0) sh_s[m] = p;
    }
    __syncthreads();
    const float mu = sh_ms[0], istd = sh_ms[1];

    float4 y4[M];
#pragma unroll
    for (int m = 0; m < M; ++m) {
        float4 a  = yzacc[m][s];
        float off = mu * sh_s[m];
        y4[m].x = istd * (a.x - off);
        y4[m].y = istd * (a.y - off);
        y4[m].z = istd * (a.z - off);
        y4[m].w = istd * (a.w - off);
    }

    // ---------------- phase B: out = z + GAIN * W^T y (z from L3) ----------
#pragma unroll 8
    for (int ci = 0; ci < CPG; ++ci) {
        float4 v = *reinterpret_cast<const float4*>(z + zoff + (size_t)ci * HW);
        const float* wc = &Wl[g * CPG + ci][0];
        float r0 = 0.f, r1 = 0.f, r2 = 0.f, r3 = 0.f;
#pragma unroll
        for (int m = 0; m < M; ++m) {
            float w = wc[(m + rot) & 7];
            r0 += w * y4[m].x; r1 += w * y4[m].y;
            r2 += w * y4[m].z; r3 += w * y4[m].w;
        }
        floatx4 o;
        o.x = v.x + GAIN * r0; o.y = v.y + GAIN * r1;
        o.z = v.z + GAIN * r2; o.w = v.w + GAIN * r3;
        __builtin_nontemporal_store(o, reinterpret_cast<floatx4*>(out + zoff + (size_t)ci * HW));
    }
}

extern "C" void kernel_launch(void* const* d_in, const int* in_sizes, int n_in,
                              void* d_out, int out_size, void* d_ws, size_t ws_size,
                              hipStream_t stream) {
    const float* z  = (const float*)d_in[0];   // (8,1024,64,64) fp32
    const float* Wd = (const float*)d_in[1];   // (8,1024) fp32
    float* out = (float*)d_out;
    float* ws  = (float*)d_ws;                 // 2 KB stat partials

    void* args[] = { (void*)&z, (void*)&Wd, (void*)&out, (void*)&ws };
    hipLaunchCooperativeKernel((const void*)fused, dim3(B * NTILE), dim3(TPB),
                               args, 0, stream);
}

// Round 15
// 95.525 us; speedup vs baseline: 1.0957x; 1.0957x over previous
//
#include <hip/hip_runtime.h>
#include <math.h>

#define B     8
#define C     1024
#define M     8
#define HW    4096
#define EPS   1e-6f
#define GAIN  0.3f

#define TPB   1024       // 16 waves; 1 block/CU (LDS-forced) -> 256 co-resident blocks
#define TILE  128        // hw per block
#define NTILE 32         // HW/TILE; grid = B*NTILE = 256
#define NG    32         // channel groups (g = tid>>5)
#define CPG   32         // channels per group
#define SLOTS 32         // float4 hw slots (s = tid&31)

#define FLAG_OFF 1024    // float index of barrier flag in ws (byte 4096)

typedef float floatx4 __attribute__((ext_vector_type(4)));

// ws: [256][2] stat partials + flag
__global__ __launch_bounds__(TPB, 4) void fused(const float* __restrict__ z,
                                                const float* __restrict__ Wd,
                                                float* __restrict__ out,
                                                float* __restrict__ ws) {
    // LDS: 32 + 64 + 4 + eps KB = ~100.3 KB -> exactly 1 block/CU
    __shared__ float Wl[C][M];                         // rotated W
    __shared__ __align__(16) float4 scr[NG][4][SLOTS]; // cross-group yz exchange
    __shared__ __align__(16) float4 yzacc[M][SLOTS];   // block's reduced yz
    __shared__ float wsred[16][2];                     // per-wave stat partials
    __shared__ float sh_s[M];
    __shared__ float sh_ms[2];

    const int tid = threadIdx.x;
    const int bid = blockIdx.x;
    const int b   = bid >> 5;
    const int t   = bid & 31;
    const int g   = tid >> 5;          // 2 groups per wave; rotation splits banks
    const int s   = tid & 31;
    const int rot = g & 7;

    // W -> rotated LDS: Wl[c][(m+(c>>5))&7] = W[m][c]
#pragma unroll
    for (int k = 0; k < 8; ++k) {
        int idx = k * TPB + tid;       // flat m*C + c
        int m = idx >> 10, c = idx & 1023;
        Wl[c][(m + (c >> 5)) & 7] = Wd[idx];
    }
    __syncthreads();

    const size_t zoff = ((size_t)(b * C + g * CPG)) * HW + t * TILE + s * 4;

    // ---------------- phase A: read z once -> stats + ym -------------------
    float4 ym[M];
#pragma unroll
    for (int m = 0; m < M; ++m) ym[m] = make_float4(0.f, 0.f, 0.f, 0.f);
    float su = 0.f, sq = 0.f;

#pragma unroll 8
    for (int ci = 0; ci < CPG; ++ci) {
        float4 v = *reinterpret_cast<const float4*>(z + zoff + (size_t)ci * HW);
        su += (v.x + v.y) + (v.z + v.w);
        sq += v.x * v.x + v.y * v.y + v.z * v.z + v.w * v.w;
        const float* wc = &Wl[g * CPG + ci][0];
#pragma unroll
        for (int m = 0; m < M; ++m) {          // static acc index
            float w = wc[(m + rot) & 7];
            ym[m].x += w * v.x; ym[m].y += w * v.y;
            ym[m].z += w * v.z; ym[m].w += w * v.w;
        }
    }

    // per-wave stats shuffle reduce
    {
        float pu = su, pq = sq;
#pragma unroll
        for (int o = 32; o > 0; o >>= 1) {
            pu += __shfl_down(pu, o);
            pq += __shfl_down(pq, o);
        }
        if ((tid & 63) == 0) {
            wsred[tid >> 6][0] = pu;
            wsred[tid >> 6][1] = pq;
        }
    }

    // cross-group yz reduce: 2 rounds of 4 m's through 64 KB scr
#pragma unroll
    for (int r = 0; r < 2; ++r) {
        __syncthreads();
#pragma unroll
        for (int mm = 0; mm < 4; ++mm) scr[g][mm][s] = ym[r * 4 + mm];
        __syncthreads();
        if (tid < 128) {
            const int mm = tid >> 5, s2 = tid & 31;
            float4 a = make_float4(0.f, 0.f, 0.f, 0.f);
#pragma unroll
            for (int g2 = 0; g2 < NG; ++g2) {
                float4 p = scr[g2][mm][s2];
                a.x += p.x; a.y += p.y; a.z += p.z; a.w += p.w;
            }
            yzacc[r * 4 + mm][s2] = a;
        }
    }
    __syncthreads();

    // block stats -> ws[bid]
    if (tid < 16) {
        float pu = wsred[tid][0], pq = wsred[tid][1];
#pragma unroll
        for (int o = 8; o > 0; o >>= 1) {
            pu += __shfl_down(pu, o);
            pq += __shfl_down(pq, o);
        }
        if (tid == 0) {
            ws[bid * 2]     = pu;
            ws[bid * 2 + 1] = pq;
        }
    }

    // ---------------- manual grid barrier (all 256 blocks co-resident) -----
    if (tid == 0) {
        unsigned* flag = reinterpret_cast<unsigned*>(ws + FLAG_OFF);
        __threadfence();                       // stats visible before signal
        atomicAdd(flag, 1u);
        for (long it = 0; it < 4000000L; ++it) {
            if (atomicAdd(flag, 0u) >= 256u) break;
            __builtin_amdgcn_s_sleep(8);
        }
        __threadfence();
    }
    __syncthreads();

    // ---------------- finalize scalars in-block ----------------------------
    if (tid < 64) {            // mu/istd from batch b's 32 block partials
        float pu = 0.f, pq = 0.f;
        if (tid < 32) {
            pu = ws[(b * 32 + tid) * 2];
            pq = ws[(b * 32 + tid) * 2 + 1];
        }
#pragma unroll
        for (int o = 16; o > 0; o >>= 1) {
            pu += __shfl_down(pu, o);
            pq += __shfl_down(pq, o);
        }
        if (tid == 0) {
            const float invN = 1.0f / (float)(C * HW);
            float mu  = pu * invN;
            float var = pq * invN - mu * mu;
            sh_ms[0] = mu;
            sh_ms[1] = 1.0f / sqrtf(var + EPS);
        }
    } else if (tid < 128) {    // s[m] from LDS W copy
        const int m = (tid - 64) >> 3, k = (tid - 64) & 7;
        float p = 0.f;
        for (int j = 0; j < 128; ++j) {
            int c = k * 128 + j;
            p += Wl[c][(m + (c >> 5)) & 7];
        }
        p += __shfl_down(p, 4);
        p += __shfl_down(p, 2);
        p += __shfl_down(p, 1);
        if (k == 0) sh_s[m] = p;
    }
    __syncthreads();
    const float mu = sh_ms[0], istd = sh_ms[1];

    float4 y4[M];
#pragma unroll
    for (int m = 0; m < M; ++m) {
        float4 a  = yzacc[m][s];
        float off = mu * sh_s[m];
        y4[m].x = istd * (a.x - off);
        y4[m].y = istd * (a.y - off);
        y4[m].z = istd * (a.z - off);
        y4[m].w = istd * (a.w - off);
    }

    // ---------------- phase B: out = z + GAIN * W^T y (z from L3) ----------
#pragma unroll 8
    for (int ci = 0; ci < CPG; ++ci) {
        float4 v = *reinterpret_cast<const float4*>(z + zoff + (size_t)ci * HW);
        const float* wc = &Wl[g * CPG + ci][0];
        float r0 = 0.f, r1 = 0.f, r2 = 0.f, r3 = 0.f;
#pragma unroll
        for (int m = 0; m < M; ++m) {
            float w = wc[(m + rot) & 7];
            r0 += w * y4[m].x; r1 += w * y4[m].y;
            r2 += w * y4[m].z; r3 += w * y4[m].w;
        }
        floatx4 o;
        o.x = v.x + GAIN * r0; o.y = v.y + GAIN * r1;
        o.z = v.z + GAIN * r2; o.w = v.w + GAIN * r3;
        __builtin_nontemporal_store(o, reinterpret_cast<floatx4*>(out + zoff + (size_t)ci * HW));
    }
}

extern "C" void kernel_launch(void* const* d_in, const int* in_sizes, int n_in,
                              void* d_out, int out_size, void* d_ws, size_t ws_size,
                              hipStream_t stream) {
    const float* z  = (const float*)d_in[0];   // (8,1024,64,64) fp32
    const float* Wd = (const float*)d_in[1];   // (8,1024) fp32
    float* out = (float*)d_out;
    float* ws  = (float*)d_ws;

    // zero the barrier flag (capture-legal async memset; deterministic per launch)
    hipMemsetAsync((char*)d_ws + FLAG_OFF * sizeof(float), 0, sizeof(unsigned), stream);
    fused<<<dim3(B * NTILE), dim3(TPB), 0, stream>>>(z, Wd, out, ws);
}